// Round 2
// baseline (601.389 us; speedup 1.0000x reference)
//
#include <hip/hip_runtime.h>

// DigitCaps routing via MFMA, u_hat never materialized.
// B=512, R=1152, J=10, O=16, I=8, JO=160, K=R*I=9216.
// s[b,jo]    = sum_k x[b,k] * Wc[k,jo],  Wc[(r,i),(j,o)] = W[r,j,o,i]*c[r,j]
// v          = s*|s|/(1+s^2)
// bias[r,j] += (1/B) sum_{i,o} W[r,j,o,i] * M[(r,i),(j,o)],  M = x_r^T @ v
// c          = softmax_r(bias)
//
// Both big contractions run as bf16 MFMA 16x16x32 with operands read
// fragment-direct from global (no LDS in the GEMMs). Wc and v are stored in
// B-fragment order: [kblk][nblk][lane][8 consecutive k] bf16.
//
// ws (bytes): bias 0 | c 46080 | wcf 92160 | vfrag 3041280 | part 3205120..

#define B_   512
#define R_   1152
#define JO_  160
#define K_   9216

typedef __attribute__((ext_vector_type(4))) float f32x4;
typedef __attribute__((ext_vector_type(8))) short bf16x8;

__device__ __forceinline__ short f2bf(float f) {
  unsigned int u = __float_as_uint(f);
  unsigned int r = (u + 0x7FFFu + ((u >> 16) & 1u)) >> 16;
  return (short)r;
}

__global__ __launch_bounds__(256) void init_kernel(float* __restrict__ bias,
                                                   float* __restrict__ c) {
  int idx = blockIdx.x * 256 + threadIdx.x;
  if (idx < R_ * 10) {
    bias[idx] = 0.0f;
    c[idx] = 1.0f / (float)R_;
  }
}

// Build Wc in B-fragment order. 184320 chunks of 16B; grid 720.
// chunk idx = (kb*10+nb)*64+lane holds k = kb*32+(lane>>4)*8+t (t=0..7),
// n = nb*16+(lane&15).  k0 is 8-aligned -> one r, i=t: 8 consecutive W elems.
__global__ __launch_bounds__(256) void wcbuild_kernel(
    const float* __restrict__ W, const float* __restrict__ c,
    short* __restrict__ wcf) {
  int idx = blockIdx.x * 256 + threadIdx.x;  // < 184320
  int lane = idx & 63;
  int rest = idx >> 6;  // kb*10+nb < 2880
  int nb = rest % 10, kb = rest / 10;
  int k0 = kb * 32 + (lane >> 4) * 8;
  int r = k0 >> 3;
  int j = nb, o = lane & 15;
  const float4* wp = (const float4*)(W + (((size_t)r * 10 + j) * 16 + o) * 8);
  float4 a = wp[0], b = wp[1];
  float cs = c[r * 10 + j];
  bf16x8 pk;
  pk[0] = f2bf(a.x * cs); pk[1] = f2bf(a.y * cs);
  pk[2] = f2bf(a.z * cs); pk[3] = f2bf(a.w * cs);
  pk[4] = f2bf(b.x * cs); pk[5] = f2bf(b.y * cs);
  pk[6] = f2bf(b.z * cs); pk[7] = f2bf(b.w * cs);
  ((bf16x8*)wcf)[idx] = pk;
}

// s-GEMM: grid (8 M-blocks, KS k-splits), 4 waves/block, wave = 16 rows x 160.
// No LDS: A-frag = 2 float4 from x + cvt; B-frags = b128 from wcf.
__global__ __launch_bounds__(256) void sgemm_kernel(
    const float* __restrict__ x, const short* __restrict__ wcf,
    float* __restrict__ part, int spk) {
  const int tid = threadIdx.x;
  const int w = tid >> 6, lane = tid & 63;
  const int m0 = blockIdx.x * 64 + w * 16;
  const int row = m0 + (lane & 15);
  const int kg = lane >> 4;
  const int ks0 = blockIdx.y * spk, ks1 = ks0 + spk;

  f32x4 acc[10] = {};
  const float* xrow = x + (size_t)row * K_ + kg * 8;
  for (int ks = ks0; ks < ks1; ++ks) {
    const float4* ap = (const float4*)(xrow + ks * 32);
    float4 a0 = ap[0], a1 = ap[1];
    bf16x8 af;
    af[0] = f2bf(a0.x); af[1] = f2bf(a0.y); af[2] = f2bf(a0.z); af[3] = f2bf(a0.w);
    af[4] = f2bf(a1.x); af[5] = f2bf(a1.y); af[6] = f2bf(a1.z); af[7] = f2bf(a1.w);
    const bf16x8* bp = (const bf16x8*)wcf + ((size_t)ks * 640 + lane);
#pragma unroll
    for (int nb = 0; nb < 10; ++nb)
      acc[nb] = __builtin_amdgcn_mfma_f32_16x16x32_bf16(af, bp[nb * 64],
                                                        acc[nb], 0, 0, 0);
  }
  // C/D: col=lane&15, row=(lane>>4)*4+q
  float* pp = part + (size_t)blockIdx.y * (B_ * JO_) +
              (size_t)(m0 + (lane >> 4) * 4) * JO_ + (lane & 15);
#pragma unroll
  for (int nb = 0; nb < 10; ++nb)
#pragma unroll
    for (int q = 0; q < 4; ++q)
      pp[q * JO_ + nb * 16] = acc[nb][q];
}

// Reduce k-splits, squash, emit v in B-fragment order (bf16) + optional out.
// grid 16 (one kb = 32 batches each), block 256.
__global__ __launch_bounds__(256) void squash_kernel(
    const float* __restrict__ part, int KS, short* __restrict__ vfrag,
    float* __restrict__ out) {
  __shared__ float vsm[32 * 162];  // stride 162: 2-way-max bank aliasing
  const int tid = threadIdx.x;
  const int kb = blockIdx.x;
#pragma unroll
  for (int q = 0; q < 20; ++q) {
    int e = q * 256 + tid;  // < 5120
    int bl = e / 160, jo = e - bl * 160;
    int b = kb * 32 + bl;
    float s = 0.0f;
    for (int ksp = 0; ksp < KS; ++ksp)
      s += part[(size_t)ksp * (B_ * JO_) + (size_t)b * JO_ + jo];
    float val = s * fabsf(s) / (1.0f + s * s);
    vsm[bl * 162 + jo] = val;
    if (out) out[(size_t)b * JO_ + jo] = val;
  }
  __syncthreads();
#pragma unroll
  for (int q = 0; q < 3; ++q) {
    int e = q * 256 + tid;
    if (e < 640) {
      int nb = e >> 6, lane = e & 63;
      bf16x8 pk;
#pragma unroll
      for (int t = 0; t < 8; ++t)
        pk[t] = f2bf(vsm[((lane >> 4) * 8 + t) * 162 + nb * 16 + (lane & 15)]);
      ((bf16x8*)vfrag)[(kb * 10 + nb) * 64 + lane] = pk;
    }
  }
}

// Agreement: per r-pair, M[16x160] = x_r^T @ v over K=B=512 (4 waves x 128),
// then bias[r,j] += (1/B) sum_{i,o} W * M, fused in-block.
__global__ __launch_bounds__(256) void agree_kernel(
    const float* __restrict__ x, const float* __restrict__ W,
    const short* __restrict__ vfrag, float* __restrict__ bias) {
  __shared__ float Msm[4][16][176];  // stride 176: rows alternate bank halves
  __shared__ float red[320];
  const int tid = threadIdx.x;
  const int w = tid >> 6, lane = tid & 63;
  const int r0 = blockIdx.x * 2;
  const int rowa = lane & 15;  // rr*8+i
  const int rr_a = rowa >> 3, i_a = rowa & 7;
  const int kg = lane >> 4;

  f32x4 acc[10] = {};
  const float* xp = x + (size_t)(r0 + rr_a) * 8 + i_a;
  for (int ks = 0; ks < 4; ++ks) {
    int b0 = w * 128 + ks * 32 + kg * 8;
    bf16x8 af;
#pragma unroll
    for (int t = 0; t < 8; ++t)
      af[t] = f2bf(xp[(size_t)(b0 + t) * K_]);
    int kb = w * 4 + ks;
    const bf16x8* bp = (const bf16x8*)vfrag + (kb * 640 + lane);
#pragma unroll
    for (int nb = 0; nb < 10; ++nb)
      acc[nb] = __builtin_amdgcn_mfma_f32_16x16x32_bf16(af, bp[nb * 64],
                                                        acc[nb], 0, 0, 0);
  }
  {
    int colc = lane & 15, rbase = (lane >> 4) * 4;
#pragma unroll
    for (int nb = 0; nb < 10; ++nb)
#pragma unroll
      for (int q = 0; q < 4; ++q)
        Msm[w][rbase + q][nb * 16 + colc] = acc[nb][q];
  }
  __syncthreads();
  for (int idx = tid; idx < 320; idx += 256) {
    int rr = idx / 160, jo = idx - rr * 160;
    int j = jo >> 4, o = jo & 15;
    float p = 0.0f;
    const float* wp = W + (((size_t)(r0 + rr) * 10 + j) * 16 + o) * 8;
#pragma unroll
    for (int i = 0; i < 8; ++i) {
      float m = Msm[0][rr * 8 + i][jo] + Msm[1][rr * 8 + i][jo] +
                Msm[2][rr * 8 + i][jo] + Msm[3][rr * 8 + i][jo];
      p += wp[i] * m;
    }
    red[idx] = p;
  }
  __syncthreads();
  if (tid < 20) {
    int rr = tid / 10, j = tid - rr * 10;
    float s = 0.0f;
#pragma unroll
    for (int o = 0; o < 16; ++o) s += red[rr * 160 + j * 16 + o];
    bias[(r0 + rr) * 10 + j] += s * (1.0f / 512.0f);
  }
}

// softmax over routes per j; fixed-order tree reductions (deterministic)
__global__ __launch_bounds__(256) void softmax_kernel(
    const float* __restrict__ bias, float* __restrict__ c) {
  __shared__ float red[256];
  const int j = blockIdx.x;
  const int tid = threadIdx.x;
  float m = -1e30f;
  for (int r = tid; r < R_; r += 256) m = fmaxf(m, bias[r * 10 + j]);
  red[tid] = m;
  __syncthreads();
  for (int s = 128; s > 0; s >>= 1) {
    if (tid < s) red[tid] = fmaxf(red[tid], red[tid + s]);
    __syncthreads();
  }
  m = red[0];
  __syncthreads();
  float sum = 0.0f;
  for (int r = tid; r < R_; r += 256) sum += expf(bias[r * 10 + j] - m);
  red[tid] = sum;
  __syncthreads();
  for (int s = 128; s > 0; s >>= 1) {
    if (tid < s) red[tid] += red[tid + s];
    __syncthreads();
  }
  float inv = 1.0f / red[0];
  for (int r = tid; r < R_; r += 256)
    c[r * 10 + j] = expf(bias[r * 10 + j] - m) * inv;
}

extern "C" void kernel_launch(void* const* d_in, const int* in_sizes, int n_in,
                              void* d_out, int out_size, void* d_ws,
                              size_t ws_size, hipStream_t stream) {
  const float* x = (const float*)d_in[0];  // [512,1152,8]
  const float* W = (const float*)d_in[1];  // [1152,10,16,8]
  float* out = (float*)d_out;              // [512,10,16,1] == [512][160]
  char* ws = (char*)d_ws;

  float* bias  = (float*)(ws);            // 11520 f
  float* c     = (float*)(ws + 46080);    // 11520 f
  short* wcf   = (short*)(ws + 92160);    // 184320*16 B = 2949120
  short* vfrag = (short*)(ws + 3041280);  // 81920*2 B = 163840
  float* part  = (float*)(ws + 3205120);  // KS * 512*160 f

  // pick largest k-split count whose partial buffer fits ws
  size_t avail = ws_size > 3205120 ? ws_size - 3205120 : 0;
  int KS = 1;
  if ((size_t)32 * 327680 <= avail) KS = 32;
  else if ((size_t)16 * 327680 <= avail) KS = 16;
  else if ((size_t)8 * 327680 <= avail) KS = 8;
  else if ((size_t)4 * 327680 <= avail) KS = 4;
  else if ((size_t)2 * 327680 <= avail) KS = 2;
  int spk = 288 / KS;

  init_kernel<<<45, 256, 0, stream>>>(bias, c);

  for (int it = 0; it < 3; ++it) {
    wcbuild_kernel<<<720, 256, 0, stream>>>(W, c, wcf);
    sgemm_kernel<<<dim3(8, KS), 256, 0, stream>>>(x, wcf, part, spk);
    squash_kernel<<<16, 256, 0, stream>>>(part, KS, vfrag,
                                          (it == 2) ? out : nullptr);
    if (it < 2) {
      agree_kernel<<<576, 256, 0, stream>>>(x, W, vfrag, bias);
      softmax_kernel<<<10, 256, 0, stream>>>(bias, c);
    }
  }
}

// Round 3
// 170.487 us; speedup vs baseline: 3.5275x; 3.5275x over previous
//
#include <hip/hip_runtime.h>

// DigitCaps routing via MFMA, u_hat never materialized.
// B=512, R=1152, J=10, O=16, I=8, JO=160, K=R*I=9216.
// s[b,jo]    = sum_k x[b,k] * Wc[k,jo],  Wc[(r,i),(j,o)] = W[r,j,o,i]*c[r,j]
// v          = s*|s|/(1+s^2)
// bias[r,j] += (1/B) sum_{i,o} W[r,j,o,i] * M[(r,i),(j,o)],  M = x_r^T @ v
// c          = softmax_r(bias)
//
// bf16 MFMA 16x16x32, operands fragment-direct from global (no LDS in GEMMs).
// x fragments (both orientations) precomputed ONCE in bf16 (x is loop-invariant);
// Wc rebuilt per iteration (c changes). Squash k-split reduce is template-KS
// (compile-time unroll -> independent loads; runtime KS was a 159us dep-chain).

#define B_   512
#define R_   1152
#define JO_  160
#define K_   9216

typedef __attribute__((ext_vector_type(4))) float f32x4;
typedef __attribute__((ext_vector_type(8))) short bf16x8;

__device__ __forceinline__ short f2bf(float f) {
  unsigned int u = __float_as_uint(f);
  unsigned int r = (u + 0x7FFFu + ((u >> 16) & 1u)) >> 16;
  return (short)r;
}

__global__ __launch_bounds__(256) void init_kernel(float* __restrict__ bias,
                                                   float* __restrict__ c) {
  int idx = blockIdx.x * 256 + threadIdx.x;
  if (idx < R_ * 10) {
    bias[idx] = 0.0f;
    c[idx] = 1.0f / (float)R_;
  }
}

// ---- one-time: x -> A-fragment order for the s-GEMM.
// frag f = m16*288+ks (m16<32, ks<288); lane l holds row m16*16+(l&15),
// k = ks*32+(l>>4)*8+t. grid 2304.
__global__ __launch_bounds__(256) void xafbuild_kernel(
    const float* __restrict__ x, short* __restrict__ xaf) {
  int gid = blockIdx.x * 256 + threadIdx.x;  // < 589824
  int lane = gid & 63, f = gid >> 6;
  int ks = f % 288, m16 = f / 288;
  int row = m16 * 16 + (lane & 15);
  int k0 = ks * 32 + (lane >> 4) * 8;
  const float4* p = (const float4*)(x + (size_t)row * K_ + k0);
  float4 a = p[0], b = p[1];
  bf16x8 pk;
  pk[0] = f2bf(a.x); pk[1] = f2bf(a.y); pk[2] = f2bf(a.z); pk[3] = f2bf(a.w);
  pk[4] = f2bf(b.x); pk[5] = f2bf(b.y); pk[6] = f2bf(b.z); pk[7] = f2bf(b.w);
  ((bf16x8*)xaf)[gid] = pk;
}

// ---- one-time: x^T -> A-fragment order for agreement.
// frag f = rp*16+kb (rp<576, kb<16); lane l holds row (l&15) of the 16
// (rr,i)-rows of r-pair rp, k = b = kb*32+(l>>4)*8+t. grid 2304.
__global__ __launch_bounds__(256) void xtfbuild_kernel(
    const float* __restrict__ x, short* __restrict__ xtf) {
  int gid = blockIdx.x * 256 + threadIdx.x;  // < 589824
  int lane = gid & 63, f = gid >> 6;
  int kb = f & 15, rp = f >> 4;
  int b0 = kb * 32 + (lane >> 4) * 8;
  const float* p = x + (size_t)b0 * K_ + rp * 16 + (lane & 15);
  bf16x8 pk;
#pragma unroll
  for (int t = 0; t < 8; ++t) pk[t] = f2bf(p[(size_t)t * K_]);
  ((bf16x8*)xtf)[gid] = pk;
}

// Build Wc in B-fragment order. frag (kb*10+nb), lane l: k=kb*32+(l>>4)*8+t,
// n=nb*16+(l&15). k0 8-aligned -> one (r, i=t) run of 8 W elems. grid 720.
__global__ __launch_bounds__(256) void wcbuild_kernel(
    const float* __restrict__ W, const float* __restrict__ c,
    short* __restrict__ wcf) {
  int idx = blockIdx.x * 256 + threadIdx.x;  // < 184320
  int lane = idx & 63;
  int rest = idx >> 6;
  int nb = rest % 10, kb = rest / 10;
  int k0 = kb * 32 + (lane >> 4) * 8;
  int r = k0 >> 3;
  int j = nb, o = lane & 15;
  const float4* wp = (const float4*)(W + (((size_t)r * 10 + j) * 16 + o) * 8);
  float4 a = wp[0], b = wp[1];
  float cs = c[r * 10 + j];
  bf16x8 pk;
  pk[0] = f2bf(a.x * cs); pk[1] = f2bf(a.y * cs);
  pk[2] = f2bf(a.z * cs); pk[3] = f2bf(a.w * cs);
  pk[4] = f2bf(b.x * cs); pk[5] = f2bf(b.y * cs);
  pk[6] = f2bf(b.z * cs); pk[7] = f2bf(b.w * cs);
  ((bf16x8*)wcf)[idx] = pk;
}

// s-GEMM: grid (8 M-blocks, KS), 4 waves; wave = 16 rows x 160, spk k-steps.
__global__ __launch_bounds__(256) void sgemm_kernel(
    const float* __restrict__ x, const short* __restrict__ xaf,
    const short* __restrict__ wcf, float* __restrict__ part, int spk) {
  const int tid = threadIdx.x;
  const int w = tid >> 6, lane = tid & 63;
  const int m16 = blockIdx.x * 4 + w;
  const int ks0 = blockIdx.y * spk;

  f32x4 acc[10] = {};
  const bf16x8* bp = (const bf16x8*)wcf + ((size_t)ks0 * 640 + lane);
  if (xaf) {
    const bf16x8* ap = (const bf16x8*)xaf + ((size_t)m16 * 288 + ks0) * 64 + lane;
    for (int ks = 0; ks < spk; ++ks) {
      bf16x8 af = ap[0];
      ap += 64;
#pragma unroll
      for (int nb = 0; nb < 10; ++nb)
        acc[nb] = __builtin_amdgcn_mfma_f32_16x16x32_bf16(af, bp[nb * 64],
                                                          acc[nb], 0, 0, 0);
      bp += 640;
    }
  } else {
    const int row = m16 * 16 + (lane & 15);
    const float* xrow = x + (size_t)row * K_ + (lane >> 4) * 8;
    for (int ks = ks0; ks < ks0 + spk; ++ks) {
      const float4* ap = (const float4*)(xrow + ks * 32);
      float4 a0 = ap[0], a1 = ap[1];
      bf16x8 af;
      af[0] = f2bf(a0.x); af[1] = f2bf(a0.y); af[2] = f2bf(a0.z); af[3] = f2bf(a0.w);
      af[4] = f2bf(a1.x); af[5] = f2bf(a1.y); af[6] = f2bf(a1.z); af[7] = f2bf(a1.w);
#pragma unroll
      for (int nb = 0; nb < 10; ++nb)
        acc[nb] = __builtin_amdgcn_mfma_f32_16x16x32_bf16(af, bp[nb * 64],
                                                          acc[nb], 0, 0, 0);
      bp += 640;
    }
  }
  // C/D: col=lane&15, row=(lane>>4)*4+q
  float* pp = part + (size_t)blockIdx.y * (B_ * JO_) +
              (size_t)(m16 * 16 + (lane >> 4) * 4) * JO_ + (lane & 15);
#pragma unroll
  for (int nb = 0; nb < 10; ++nb)
#pragma unroll
    for (int q = 0; q < 4; ++q)
      pp[q * JO_ + nb * 16] = acc[nb][q];
}

// Reduce k-splits (compile-time unrolled!), squash, emit v fragments + out.
// grid 16 (one kb = 32 batches), block 256.
template <int KS>
__global__ __launch_bounds__(256) void squash_kernel(
    const float* __restrict__ part, short* __restrict__ vfrag,
    float* __restrict__ out) {
  __shared__ float vsm[32 * 162];
  const int tid = threadIdx.x;
  const int kb = blockIdx.x;
#pragma unroll
  for (int q = 0; q < 20; ++q) {
    int e = q * 256 + tid;  // < 5120
    int bl = e / 160, jo = e - bl * 160;
    int b = kb * 32 + bl;
    const float* pe = part + (size_t)b * JO_ + jo;
    float s = 0.0f;
#pragma unroll
    for (int ksp = 0; ksp < KS; ++ksp) s += pe[(size_t)ksp * (B_ * JO_)];
    float val = s * fabsf(s) / (1.0f + s * s);
    vsm[bl * 162 + jo] = val;
    if (out) out[(size_t)b * JO_ + jo] = val;
  }
  __syncthreads();
#pragma unroll
  for (int q = 0; q < 3; ++q) {
    int e = q * 256 + tid;
    if (e < 640) {
      int nb = e >> 6, lane = e & 63;
      bf16x8 pk;
#pragma unroll
      for (int t = 0; t < 8; ++t)
        pk[t] = f2bf(vsm[((lane >> 4) * 8 + t) * 162 + nb * 16 + (lane & 15)]);
      ((bf16x8*)vfrag)[(kb * 10 + nb) * 64 + lane] = pk;
    }
  }
}

// Agreement: per r-pair, M[16x160] = x_r^T @ v over K=B=512 (4 waves x 128),
// then bias[r,j] += (1/B) sum_{i,o} W * M, fused in-block. grid 576.
__global__ __launch_bounds__(256) void agree_kernel(
    const float* __restrict__ x, const short* __restrict__ xtf,
    const float* __restrict__ W, const short* __restrict__ vfrag,
    float* __restrict__ bias) {
  __shared__ float Msm[4][16][176];
  __shared__ float red[320];
  const int tid = threadIdx.x;
  const int w = tid >> 6, lane = tid & 63;
  const int rp = blockIdx.x;
  const int r0 = rp * 2;

  f32x4 acc[10] = {};
  if (xtf) {
    const bf16x8* ap = (const bf16x8*)xtf + ((size_t)rp * 16 + w * 4) * 64 + lane;
    const bf16x8* bp = (const bf16x8*)vfrag + ((size_t)(w * 4) * 640 + lane);
#pragma unroll
    for (int ks = 0; ks < 4; ++ks) {
      bf16x8 af = ap[0];
      ap += 64;
#pragma unroll
      for (int nb = 0; nb < 10; ++nb)
        acc[nb] = __builtin_amdgcn_mfma_f32_16x16x32_bf16(af, bp[nb * 64],
                                                          acc[nb], 0, 0, 0);
      bp += 640;
    }
  } else {
    const int rowa = lane & 15;
    const float* xp = x + (size_t)rp * 16 + rowa;
    for (int ks = 0; ks < 4; ++ks) {
      int b0 = w * 128 + ks * 32 + (lane >> 4) * 8;
      bf16x8 af;
#pragma unroll
      for (int t = 0; t < 8; ++t) af[t] = f2bf(xp[(size_t)(b0 + t) * K_]);
      const bf16x8* bp = (const bf16x8*)vfrag + ((w * 4 + ks) * 640 + lane);
#pragma unroll
      for (int nb = 0; nb < 10; ++nb)
        acc[nb] = __builtin_amdgcn_mfma_f32_16x16x32_bf16(af, bp[nb * 64],
                                                          acc[nb], 0, 0, 0);
    }
  }
  {
    int colc = lane & 15, rbase = (lane >> 4) * 4;
#pragma unroll
    for (int nb = 0; nb < 10; ++nb)
#pragma unroll
      for (int q = 0; q < 4; ++q)
        Msm[w][rbase + q][nb * 16 + colc] = acc[nb][q];
  }
  __syncthreads();
  for (int idx = tid; idx < 320; idx += 256) {
    int rr = idx / 160, jo = idx - rr * 160;
    int j = jo >> 4, o = jo & 15;
    float p = 0.0f;
    const float* wp = W + (((size_t)(r0 + rr) * 10 + j) * 16 + o) * 8;
#pragma unroll
    for (int i = 0; i < 8; ++i) {
      float m = Msm[0][rr * 8 + i][jo] + Msm[1][rr * 8 + i][jo] +
                Msm[2][rr * 8 + i][jo] + Msm[3][rr * 8 + i][jo];
      p += wp[i] * m;
    }
    red[idx] = p;
  }
  __syncthreads();
  if (tid < 20) {
    int rr = tid / 10, j = tid - rr * 10;
    float s = 0.0f;
#pragma unroll
    for (int o = 0; o < 16; ++o) s += red[rr * 160 + j * 16 + o];
    bias[(r0 + rr) * 10 + j] += s * (1.0f / 512.0f);
  }
}

// softmax over routes per j; fixed-order tree reductions (deterministic)
__global__ __launch_bounds__(256) void softmax_kernel(
    const float* __restrict__ bias, float* __restrict__ c) {
  __shared__ float red[256];
  const int j = blockIdx.x;
  const int tid = threadIdx.x;
  float m = -1e30f;
  for (int r = tid; r < R_; r += 256) m = fmaxf(m, bias[r * 10 + j]);
  red[tid] = m;
  __syncthreads();
  for (int s = 128; s > 0; s >>= 1) {
    if (tid < s) red[tid] = fmaxf(red[tid], red[tid + s]);
    __syncthreads();
  }
  m = red[0];
  __syncthreads();
  float sum = 0.0f;
  for (int r = tid; r < R_; r += 256) sum += expf(bias[r * 10 + j] - m);
  red[tid] = sum;
  __syncthreads();
  for (int s = 128; s > 0; s >>= 1) {
    if (tid < s) red[tid] += red[tid + s];
    __syncthreads();
  }
  float inv = 1.0f / red[0];
  for (int r = tid; r < R_; r += 256)
    c[r * 10 + j] = expf(bias[r * 10 + j] - m) * inv;
}

extern "C" void kernel_launch(void* const* d_in, const int* in_sizes, int n_in,
                              void* d_out, int out_size, void* d_ws,
                              size_t ws_size, hipStream_t stream) {
  const float* x = (const float*)d_in[0];  // [512,1152,8]
  const float* W = (const float*)d_in[1];  // [1152,10,16,8]
  float* out = (float*)d_out;              // [512][160]
  char* ws = (char*)d_ws;

  const size_t BASE = 3205120;       // bias|c|wcf|vfrag
  const size_t PARTB = 327680;       // one k-split plane (512*160*4)
  const size_t XAFB = 9437184, XTFB = 9437184;

  float* bias  = (float*)(ws);
  float* c     = (float*)(ws + 46080);
  short* wcf   = (short*)(ws + 92160);
  short* vfrag = (short*)(ws + 3041280);

  size_t avail = ws_size > BASE ? ws_size - BASE : 0;
  int KS = 1;
  bool useXaf = false, useXtf = false;
  if (avail >= 32 * PARTB + XAFB + XTFB) { KS = 32; useXaf = useXtf = true; }
  else if (avail >= 16 * PARTB + XAFB + XTFB) { KS = 16; useXaf = useXtf = true; }
  else if (avail >= 16 * PARTB + XAFB) { KS = 16; useXaf = true; }
  else if (avail >= 16 * PARTB) KS = 16;
  else if (avail >= 8 * PARTB) KS = 8;
  else if (avail >= 4 * PARTB) KS = 4;
  else if (avail >= 2 * PARTB) KS = 2;
  int spk = 288 / KS;

  size_t cur = BASE;
  short* xaf = nullptr;
  short* xtf = nullptr;
  if (useXaf) { xaf = (short*)(ws + cur); cur += XAFB; }
  if (useXtf) { xtf = (short*)(ws + cur); cur += XTFB; }
  float* part = (float*)(ws + cur);

  init_kernel<<<45, 256, 0, stream>>>(bias, c);
  if (useXaf) xafbuild_kernel<<<2304, 256, 0, stream>>>(x, xaf);
  if (useXtf) xtfbuild_kernel<<<2304, 256, 0, stream>>>(x, xtf);

  for (int it = 0; it < 3; ++it) {
    wcbuild_kernel<<<720, 256, 0, stream>>>(W, c, wcf);
    sgemm_kernel<<<dim3(8, KS), 256, 0, stream>>>(x, xaf, wcf, part, spk);
    float* o = (it == 2) ? out : nullptr;
    switch (KS) {
      case 32: squash_kernel<32><<<16, 256, 0, stream>>>(part, vfrag, o); break;
      case 16: squash_kernel<16><<<16, 256, 0, stream>>>(part, vfrag, o); break;
      case 8:  squash_kernel<8><<<16, 256, 0, stream>>>(part, vfrag, o); break;
      case 4:  squash_kernel<4><<<16, 256, 0, stream>>>(part, vfrag, o); break;
      case 2:  squash_kernel<2><<<16, 256, 0, stream>>>(part, vfrag, o); break;
      default: squash_kernel<1><<<16, 256, 0, stream>>>(part, vfrag, o); break;
    }
    if (it < 2) {
      agree_kernel<<<576, 256, 0, stream>>>(x, xtf, W, vfrag, bias);
      softmax_kernel<<<10, 256, 0, stream>>>(bias, c);
    }
  }
}

// Round 4
// 98.306 us; speedup vs baseline: 6.1175x; 1.7342x over previous
//
#include <hip/hip_runtime.h>

// DigitCaps routing via MFMA, u_hat never materialized.
// B=512, R=1152, J=10, O=16, I=8, JO=160, K=R*I=9216.
// s[b,jo]    = sum_k x[b,k] * Wc[k,jo],  Wc[(r,i),(j,o)] = W[r,j,o,i]*c[r,j]
// v          = s*|s|/(1+s^2)
// bias[r,j] += (1/B) sum_{i,o} W[r,j,o,i] * M[(r,i),(j,o)],  M = x_r^T @ v
// c          = softmax_r(bias)
//
// bf16 MFMA 16x16x32, operands fragment-direct from global (no LDS in GEMMs).
// x fragments precomputed once (loop-invariant). Squash: 1 element/thread,
// explicit pv[KS] load array (grid-16 version was a 50us latency chain at
// 0.7% occupancy - parallelism, not unrolling, was the fix).

#define B_   512
#define R_   1152
#define JO_  160
#define K_   9216

typedef __attribute__((ext_vector_type(4))) float f32x4;
typedef __attribute__((ext_vector_type(8))) short bf16x8;

__device__ __forceinline__ short f2bf(float f) {
  unsigned int u = __float_as_uint(f);
  unsigned int r = (u + 0x7FFFu + ((u >> 16) & 1u)) >> 16;
  return (short)r;
}

__global__ __launch_bounds__(256) void init_kernel(float* __restrict__ bias,
                                                   float* __restrict__ c) {
  int idx = blockIdx.x * 256 + threadIdx.x;
  if (idx < R_ * 10) {
    bias[idx] = 0.0f;
    c[idx] = 1.0f / (float)R_;
  }
}

// ---- one-time: x -> A-fragment order for the s-GEMM.
// frag f = m16*288+ks; lane l: row m16*16+(l&15), k = ks*32+(l>>4)*8+t.
__global__ __launch_bounds__(256) void xafbuild_kernel(
    const float* __restrict__ x, short* __restrict__ xaf) {
  int gid = blockIdx.x * 256 + threadIdx.x;  // < 589824
  int lane = gid & 63, f = gid >> 6;
  int ks = f % 288, m16 = f / 288;
  int row = m16 * 16 + (lane & 15);
  int k0 = ks * 32 + (lane >> 4) * 8;
  const float4* p = (const float4*)(x + (size_t)row * K_ + k0);
  float4 a = p[0], b = p[1];
  bf16x8 pk;
  pk[0] = f2bf(a.x); pk[1] = f2bf(a.y); pk[2] = f2bf(a.z); pk[3] = f2bf(a.w);
  pk[4] = f2bf(b.x); pk[5] = f2bf(b.y); pk[6] = f2bf(b.z); pk[7] = f2bf(b.w);
  ((bf16x8*)xaf)[gid] = pk;
}

// ---- one-time: x^T -> A-fragment order for agreement.
// frag f = rp*16+kb; lane l: row (l&15) of r-pair rp, k = b = kb*32+(l>>4)*8+t.
__global__ __launch_bounds__(256) void xtfbuild_kernel(
    const float* __restrict__ x, short* __restrict__ xtf) {
  int gid = blockIdx.x * 256 + threadIdx.x;  // < 589824
  int lane = gid & 63, f = gid >> 6;
  int kb = f & 15, rp = f >> 4;
  int b0 = kb * 32 + (lane >> 4) * 8;
  const float* p = x + (size_t)b0 * K_ + rp * 16 + (lane & 15);
  bf16x8 pk;
#pragma unroll
  for (int t = 0; t < 8; ++t) pk[t] = f2bf(p[(size_t)t * K_]);
  ((bf16x8*)xtf)[gid] = pk;
}

// Build Wc in B-fragment order. frag (kb*10+nb), lane l: k=kb*32+(l>>4)*8+t,
// n=nb*16+(l&15). grid 720.
__global__ __launch_bounds__(256) void wcbuild_kernel(
    const float* __restrict__ W, const float* __restrict__ c,
    short* __restrict__ wcf) {
  int idx = blockIdx.x * 256 + threadIdx.x;  // < 184320
  int lane = idx & 63;
  int rest = idx >> 6;
  int nb = rest % 10, kb = rest / 10;
  int k0 = kb * 32 + (lane >> 4) * 8;
  int r = k0 >> 3;
  int j = nb, o = lane & 15;
  const float4* wp = (const float4*)(W + (((size_t)r * 10 + j) * 16 + o) * 8);
  float4 a = wp[0], b = wp[1];
  float cs = c[r * 10 + j];
  bf16x8 pk;
  pk[0] = f2bf(a.x * cs); pk[1] = f2bf(a.y * cs);
  pk[2] = f2bf(a.z * cs); pk[3] = f2bf(a.w * cs);
  pk[4] = f2bf(b.x * cs); pk[5] = f2bf(b.y * cs);
  pk[6] = f2bf(b.z * cs); pk[7] = f2bf(b.w * cs);
  ((bf16x8*)wcf)[idx] = pk;
}

// s-GEMM: grid (8 M-blocks, KS), 4 waves; wave = 16 rows x 160, spk k-steps.
__global__ __launch_bounds__(256) void sgemm_kernel(
    const float* __restrict__ x, const short* __restrict__ xaf,
    const short* __restrict__ wcf, float* __restrict__ part, int spk) {
  const int tid = threadIdx.x;
  const int w = tid >> 6, lane = tid & 63;
  const int m16 = blockIdx.x * 4 + w;
  const int ks0 = blockIdx.y * spk;

  f32x4 acc[10] = {};
  const bf16x8* bp = (const bf16x8*)wcf + ((size_t)ks0 * 640 + lane);
  if (xaf) {
    const bf16x8* ap = (const bf16x8*)xaf + ((size_t)m16 * 288 + ks0) * 64 + lane;
    for (int ks = 0; ks < spk; ++ks) {
      bf16x8 af = ap[0];
      ap += 64;
#pragma unroll
      for (int nb = 0; nb < 10; ++nb)
        acc[nb] = __builtin_amdgcn_mfma_f32_16x16x32_bf16(af, bp[nb * 64],
                                                          acc[nb], 0, 0, 0);
      bp += 640;
    }
  } else {
    const int row = m16 * 16 + (lane & 15);
    const float* xrow = x + (size_t)row * K_ + (lane >> 4) * 8;
    for (int ks = ks0; ks < ks0 + spk; ++ks) {
      const float4* ap = (const float4*)(xrow + ks * 32);
      float4 a0 = ap[0], a1 = ap[1];
      bf16x8 af;
      af[0] = f2bf(a0.x); af[1] = f2bf(a0.y); af[2] = f2bf(a0.z); af[3] = f2bf(a0.w);
      af[4] = f2bf(a1.x); af[5] = f2bf(a1.y); af[6] = f2bf(a1.z); af[7] = f2bf(a1.w);
#pragma unroll
      for (int nb = 0; nb < 10; ++nb)
        acc[nb] = __builtin_amdgcn_mfma_f32_16x16x32_bf16(af, bp[nb * 64],
                                                          acc[nb], 0, 0, 0);
      bp += 640;
    }
  }
  // C/D: col=lane&15, row=(lane>>4)*4+q
  float* pp = part + (size_t)blockIdx.y * (B_ * JO_) +
              (size_t)(m16 * 16 + (lane >> 4) * 4) * JO_ + (lane & 15);
#pragma unroll
  for (int nb = 0; nb < 10; ++nb)
#pragma unroll
    for (int q = 0; q < 4; ++q)
      pp[q * JO_ + nb * 16] = acc[nb][q];
}

// Reduce k-splits + squash. grid 160 (one (kb,nb) 32x16 tile), block 512,
// 1 element/thread, explicit pv[KS] so loads issue back-to-back.
// First 64 threads assemble the bf16 v-fragment via a small LDS tile.
template <int KS>
__global__ __launch_bounds__(512) void squash_kernel(
    const float* __restrict__ part, short* __restrict__ vfrag,
    float* __restrict__ out) {
  __shared__ float vsm[32][17];
  const int tid = threadIdx.x;  // 0..511
  const int kb = blockIdx.x / 10, nb = blockIdx.x - (blockIdx.x / 10) * 10;
  const int bl = tid >> 4, col = tid & 15;
  const int b = kb * 32 + bl, jo = nb * 16 + col;
  const float* pe = part + (size_t)b * JO_ + jo;
  float pv[KS];
#pragma unroll
  for (int ks = 0; ks < KS; ++ks) pv[ks] = pe[(size_t)ks * (B_ * JO_)];
  float s = 0.0f;
#pragma unroll
  for (int ks = 0; ks < KS; ++ks) s += pv[ks];
  float val = s * fabsf(s) / (1.0f + s * s);
  if (out) out[(size_t)b * JO_ + jo] = val;
  if (vfrag) {
    vsm[bl][col] = val;
    __syncthreads();
    if (tid < 64) {
      bf16x8 pk;
#pragma unroll
      for (int t = 0; t < 8; ++t)
        pk[t] = f2bf(vsm[(tid >> 4) * 8 + t][tid & 15]);
      ((bf16x8*)vfrag)[(size_t)blockIdx.x * 64 + tid] = pk;
    }
  }
}

// Agreement: per r-pair, M[16x160] = x_r^T @ v over K=B=512 (4 waves x 128),
// then bias[r,j] += (1/B) sum_{i,o} W * M, fused in-block. grid 576.
__global__ __launch_bounds__(256) void agree_kernel(
    const float* __restrict__ x, const short* __restrict__ xtf,
    const float* __restrict__ W, const short* __restrict__ vfrag,
    float* __restrict__ bias) {
  __shared__ float Msm[4][16][176];
  __shared__ float red[320];
  const int tid = threadIdx.x;
  const int w = tid >> 6, lane = tid & 63;
  const int rp = blockIdx.x;
  const int r0 = rp * 2;

  f32x4 acc[10] = {};
  if (xtf) {
    const bf16x8* ap = (const bf16x8*)xtf + ((size_t)rp * 16 + w * 4) * 64 + lane;
    const bf16x8* bp = (const bf16x8*)vfrag + ((size_t)(w * 4) * 640 + lane);
#pragma unroll
    for (int ks = 0; ks < 4; ++ks) {
      bf16x8 af = ap[0];
      ap += 64;
#pragma unroll
      for (int nb = 0; nb < 10; ++nb)
        acc[nb] = __builtin_amdgcn_mfma_f32_16x16x32_bf16(af, bp[nb * 64],
                                                          acc[nb], 0, 0, 0);
      bp += 640;
    }
  } else {
    const int rowa = lane & 15;
    const float* xp = x + (size_t)rp * 16 + rowa;
    for (int ks = 0; ks < 4; ++ks) {
      int b0 = w * 128 + ks * 32 + (lane >> 4) * 8;
      bf16x8 af;
#pragma unroll
      for (int t = 0; t < 8; ++t) af[t] = f2bf(xp[(size_t)(b0 + t) * K_]);
      const bf16x8* bp = (const bf16x8*)vfrag + ((w * 4 + ks) * 640 + lane);
#pragma unroll
      for (int nb = 0; nb < 10; ++nb)
        acc[nb] = __builtin_amdgcn_mfma_f32_16x16x32_bf16(af, bp[nb * 64],
                                                          acc[nb], 0, 0, 0);
    }
  }
  {
    int colc = lane & 15, rbase = (lane >> 4) * 4;
#pragma unroll
    for (int nb = 0; nb < 10; ++nb)
#pragma unroll
      for (int q = 0; q < 4; ++q)
        Msm[w][rbase + q][nb * 16 + colc] = acc[nb][q];
  }
  __syncthreads();
  for (int idx = tid; idx < 320; idx += 256) {
    int rr = idx / 160, jo = idx - rr * 160;
    int j = jo >> 4, o = jo & 15;
    float p = 0.0f;
    const float* wp = W + (((size_t)(r0 + rr) * 10 + j) * 16 + o) * 8;
#pragma unroll
    for (int i = 0; i < 8; ++i) {
      float m = Msm[0][rr * 8 + i][jo] + Msm[1][rr * 8 + i][jo] +
                Msm[2][rr * 8 + i][jo] + Msm[3][rr * 8 + i][jo];
      p += wp[i] * m;
    }
    red[idx] = p;
  }
  __syncthreads();
  if (tid < 20) {
    int rr = tid / 10, j = tid - rr * 10;
    float s = 0.0f;
#pragma unroll
    for (int o = 0; o < 16; ++o) s += red[rr * 160 + j * 16 + o];
    bias[(r0 + rr) * 10 + j] += s * (1.0f / 512.0f);
  }
}

// softmax over routes per j; fixed-order tree reductions (deterministic)
__global__ __launch_bounds__(256) void softmax_kernel(
    const float* __restrict__ bias, float* __restrict__ c) {
  __shared__ float red[256];
  const int j = blockIdx.x;
  const int tid = threadIdx.x;
  float m = -1e30f;
  for (int r = tid; r < R_; r += 256) m = fmaxf(m, bias[r * 10 + j]);
  red[tid] = m;
  __syncthreads();
  for (int s = 128; s > 0; s >>= 1) {
    if (tid < s) red[tid] = fmaxf(red[tid], red[tid + s]);
    __syncthreads();
  }
  m = red[0];
  __syncthreads();
  float sum = 0.0f;
  for (int r = tid; r < R_; r += 256) sum += expf(bias[r * 10 + j] - m);
  red[tid] = sum;
  __syncthreads();
  for (int s = 128; s > 0; s >>= 1) {
    if (tid < s) red[tid] += red[tid + s];
    __syncthreads();
  }
  float inv = 1.0f / red[0];
  for (int r = tid; r < R_; r += 256)
    c[r * 10 + j] = expf(bias[r * 10 + j] - m) * inv;
}

extern "C" void kernel_launch(void* const* d_in, const int* in_sizes, int n_in,
                              void* d_out, int out_size, void* d_ws,
                              size_t ws_size, hipStream_t stream) {
  const float* x = (const float*)d_in[0];  // [512,1152,8]
  const float* W = (const float*)d_in[1];  // [1152,10,16,8]
  float* out = (float*)d_out;              // [512][160]
  char* ws = (char*)d_ws;

  const size_t BASE = 3205120;       // bias|c|wcf|vfrag
  const size_t PARTB = 327680;       // one k-split plane (512*160*4)
  const size_t XAFB = 9437184, XTFB = 9437184;

  float* bias  = (float*)(ws);
  float* c     = (float*)(ws + 46080);
  short* wcf   = (short*)(ws + 92160);
  short* vfrag = (short*)(ws + 3041280);

  size_t avail = ws_size > BASE ? ws_size - BASE : 0;
  int KS = 1;
  bool useXaf = false, useXtf = false;
  if (avail >= 32 * PARTB + XAFB + XTFB) { KS = 32; useXaf = useXtf = true; }
  else if (avail >= 16 * PARTB + XAFB + XTFB) { KS = 16; useXaf = useXtf = true; }
  else if (avail >= 16 * PARTB + XAFB) { KS = 16; useXaf = true; }
  else if (avail >= 16 * PARTB) KS = 16;
  else if (avail >= 8 * PARTB) KS = 8;
  else if (avail >= 4 * PARTB) KS = 4;
  else if (avail >= 2 * PARTB) KS = 2;
  int spk = 288 / KS;

  size_t cur = BASE;
  short* xaf = nullptr;
  short* xtf = nullptr;
  if (useXaf) { xaf = (short*)(ws + cur); cur += XAFB; }
  if (useXtf) { xtf = (short*)(ws + cur); cur += XTFB; }
  float* part = (float*)(ws + cur);

  init_kernel<<<45, 256, 0, stream>>>(bias, c);
  if (useXaf) xafbuild_kernel<<<2304, 256, 0, stream>>>(x, xaf);
  if (useXtf) xtfbuild_kernel<<<2304, 256, 0, stream>>>(x, xtf);

  for (int it = 0; it < 3; ++it) {
    wcbuild_kernel<<<720, 256, 0, stream>>>(W, c, wcf);
    sgemm_kernel<<<dim3(8, KS), 256, 0, stream>>>(x, xaf, wcf, part, spk);
    short* vf = (it < 2) ? vfrag : nullptr;
    float* o = (it == 2) ? out : nullptr;
    switch (KS) {
      case 32: squash_kernel<32><<<160, 512, 0, stream>>>(part, vf, o); break;
      case 16: squash_kernel<16><<<160, 512, 0, stream>>>(part, vf, o); break;
      case 8:  squash_kernel<8><<<160, 512, 0, stream>>>(part, vf, o); break;
      case 4:  squash_kernel<4><<<160, 512, 0, stream>>>(part, vf, o); break;
      case 2:  squash_kernel<2><<<160, 512, 0, stream>>>(part, vf, o); break;
      default: squash_kernel<1><<<160, 512, 0, stream>>>(part, vf, o); break;
    }
    if (it < 2) {
      agree_kernel<<<576, 256, 0, stream>>>(x, xtf, W, vfrag, bias);
      softmax_kernel<<<10, 256, 0, stream>>>(bias, c);
    }
  }
}